// Round 1
// baseline (1278.438 us; speedup 1.0000x reference)
//
#include <hip/hip_runtime.h>

// ---- problem constants ----
#define B_  4
#define S_  2048
#define H_  1024
#define NH_ 16
#define HD_ 64
#define FF_ 4096
#define M_  (B_*S_)   // 8192 rows

typedef __bf16 bf16x8 __attribute__((ext_vector_type(8)));
typedef float  f32x4  __attribute__((ext_vector_type(4)));
typedef unsigned short ushort8v __attribute__((ext_vector_type(8)));
typedef unsigned short ushort4v __attribute__((ext_vector_type(4)));

__device__ __forceinline__ unsigned short f2bf(float f) {
  unsigned int u = __float_as_uint(f);
  u += 0x7fffu + ((u >> 16) & 1u);   // round-to-nearest-even
  return (unsigned short)(u >> 16);
}
__device__ __forceinline__ float bf2f(unsigned short h) {
  return __uint_as_float(((unsigned int)h) << 16);
}

// ---------------- cast fp32 -> bf16 ----------------
__global__ __launch_bounds__(256) void cast_f32_bf16(const float* __restrict__ in,
                                                     unsigned short* __restrict__ out,
                                                     int n4) {
  int i = blockIdx.x * 256 + threadIdx.x;
  if (i >= n4) return;
  float4 v = reinterpret_cast<const float4*>(in)[i];
  ushort4v o;
  o[0] = f2bf(v.x); o[1] = f2bf(v.y); o[2] = f2bf(v.z); o[3] = f2bf(v.w);
  reinterpret_cast<ushort4v*>(out)[i] = o;
}

// ---------------- GEMM: C[M,N] = act(A[M,K] @ B[K,N] + bias) ----------------
// 128x128 tile, BK=32, 4 waves (2x2 of 64x64), 16x16x32 bf16 MFMA.
// ACT: 0 = none, 1 = exact gelu.  OUT_F32: 1 -> float out, 0 -> bf16 out.
template<int ACT, int OUT_F32>
__global__ __launch_bounds__(256) void gemm_bf16(const unsigned short* __restrict__ A,
                                                 const unsigned short* __restrict__ Bm,
                                                 const float* __restrict__ bias,
                                                 void* __restrict__ C,
                                                 int M, int N, int K) {
  // stride 40 elems = 80B (16B multiple, breaks pow2 bank pattern)
  __shared__ unsigned short As[128 * 40];
  __shared__ unsigned short Bs[128 * 40];   // stored transposed: Bs[n][k]

  const int tid  = threadIdx.x;
  const int wave = tid >> 6;
  const int lane = tid & 63;
  const int kg   = lane >> 4;      // 0..3
  const int lr   = lane & 15;      // 0..15
  const int m0 = blockIdx.x * 128;
  const int n0 = blockIdx.y * 128;
  const int wr = (wave >> 1) * 64; // wave row offset in tile
  const int wc = (wave & 1) * 64;  // wave col offset in tile

  f32x4 acc[4][4] = {};

  for (int k0 = 0; k0 < K; k0 += 32) {
    __syncthreads();
    // stage A tile: 128 rows x 32 k (row-major, contiguous k)
#pragma unroll
    for (int i = 0; i < 2; ++i) {
      int cid = tid + i * 256;          // 0..511
      int r   = cid >> 2;               // 0..127
      int kc  = (cid & 3) * 8;          // 0,8,16,24
      ushort8v v = *reinterpret_cast<const ushort8v*>(&A[(size_t)(m0 + r) * K + k0 + kc]);
      *reinterpret_cast<ushort8v*>(&As[r * 40 + kc]) = v;
    }
    // stage B tile transposed: Bs[n][k]
#pragma unroll
    for (int i = 0; i < 2; ++i) {
      int cid = tid + i * 256;          // 0..511
      int kk  = cid >> 4;               // 0..31
      int nc  = (cid & 15) * 8;         // 0..120
      ushort8v v = *reinterpret_cast<const ushort8v*>(&Bm[(size_t)(k0 + kk) * N + n0 + nc]);
#pragma unroll
      for (int j = 0; j < 8; ++j) Bs[(nc + j) * 40 + kk] = v[j];
    }
    __syncthreads();

    bf16x8 af[4], bfr[4];
#pragma unroll
    for (int mi = 0; mi < 4; ++mi)
      af[mi] = *reinterpret_cast<const bf16x8*>(&As[(wr + mi * 16 + lr) * 40 + kg * 8]);
#pragma unroll
    for (int ni = 0; ni < 4; ++ni)
      bfr[ni] = *reinterpret_cast<const bf16x8*>(&Bs[(wc + ni * 16 + lr) * 40 + kg * 8]);
#pragma unroll
    for (int mi = 0; mi < 4; ++mi)
#pragma unroll
      for (int ni = 0; ni < 4; ++ni)
        acc[mi][ni] = __builtin_amdgcn_mfma_f32_16x16x32_bf16(af[mi], bfr[ni], acc[mi][ni], 0, 0, 0);
  }

  // epilogue: D row = (lane>>4)*4 + reg, col = lane&15 (verified layout)
#pragma unroll
  for (int mi = 0; mi < 4; ++mi) {
#pragma unroll
    for (int ni = 0; ni < 4; ++ni) {
      int col = n0 + wc + ni * 16 + lr;
      float bc = bias ? bias[col] : 0.0f;
#pragma unroll
      for (int r = 0; r < 4; ++r) {
        int row = m0 + wr + mi * 16 + kg * 4 + r;
        float v = acc[mi][ni][r] + bc;
        if (ACT == 1) v = 0.5f * v * (1.0f + erff(v * 0.70710678118f));
        if (OUT_F32) reinterpret_cast<float*>(C)[(size_t)row * N + col] = v;
        else reinterpret_cast<unsigned short*>(C)[(size_t)row * N + col] = f2bf(v);
      }
    }
  }
}

// ---------------- flash attention ----------------
// grid: (S/64, B*NH). 4 waves per block, each wave owns 16 q rows.
__global__ __launch_bounds__(256) void attn_fwd(const unsigned short* __restrict__ Q,
                                                const unsigned short* __restrict__ Kb,
                                                const unsigned short* __restrict__ V,
                                                unsigned short* __restrict__ O) {
  __shared__ unsigned short Ks[64 * 72];        // K tile row-major [kk][d]
  __shared__ unsigned short Vt[64 * 72];        // V tile transposed [d][kk]
  __shared__ unsigned short Ps[4 * 16 * 72];    // per-wave P tiles [q][kk]

  const int tid  = threadIdx.x;
  const int wave = tid >> 6;
  const int lane = tid & 63;
  const int kg   = lane >> 4;
  const int lr   = lane & 15;
  const int qt = blockIdx.x;            // 0..31
  const int bh = blockIdx.y;            // 0..63
  const int b  = bh >> 4;
  const int h  = bh & 15;
  const size_t rowbase = (size_t)b * S_;
  const int hcol = h * 64;
  const int q0 = qt * 64 + wave * 16;

  // Q fragments live in registers for the whole kernel
  bf16x8 qf[2];
#pragma unroll
  for (int d = 0; d < 2; ++d)
    qf[d] = *reinterpret_cast<const bf16x8*>(&Q[(rowbase + q0 + lr) * H_ + hcol + d * 32 + kg * 8]);

  f32x4 ctx[4] = {};
  float m_i[4], l_i[4];
#pragma unroll
  for (int r = 0; r < 4; ++r) { m_i[r] = -1e30f; l_i[r] = 0.0f; }

  for (int kt = 0; kt < S_ / 64; ++kt) {
    __syncthreads();
    // stage K tile (row-major) and V tile (transposed)
#pragma unroll
    for (int i = 0; i < 2; ++i) {
      int cid = tid + i * 256;           // 0..511
      int r   = cid >> 3;                // 0..63
      int dc  = (cid & 7) * 8;           // 0..56
      ushort8v kv = *reinterpret_cast<const ushort8v*>(&Kb[(rowbase + kt * 64 + r) * H_ + hcol + dc]);
      *reinterpret_cast<ushort8v*>(&Ks[r * 72 + dc]) = kv;
      ushort8v vv = *reinterpret_cast<const ushort8v*>(&V[(rowbase + kt * 64 + r) * H_ + hcol + dc]);
#pragma unroll
      for (int j = 0; j < 8; ++j) Vt[(dc + j) * 72 + r] = vv[j];
    }
    __syncthreads();

    // S = Q K^T / 8 : 4 col-fragments of 16
    f32x4 s[4];
#pragma unroll
    for (int nf = 0; nf < 4; ++nf) {
      bf16x8 kf0 = *reinterpret_cast<const bf16x8*>(&Ks[(nf * 16 + lr) * 72 + kg * 8]);
      bf16x8 kf1 = *reinterpret_cast<const bf16x8*>(&Ks[(nf * 16 + lr) * 72 + 32 + kg * 8]);
      f32x4 z = {0.0f, 0.0f, 0.0f, 0.0f};
      z = __builtin_amdgcn_mfma_f32_16x16x32_bf16(qf[0], kf0, z, 0, 0, 0);
      z = __builtin_amdgcn_mfma_f32_16x16x32_bf16(qf[1], kf1, z, 0, 0, 0);
      s[nf] = z;
    }

    // online softmax per q-row (row = kg*4 + r, replicated over 16 lanes)
#pragma unroll
    for (int r = 0; r < 4; ++r) {
      float mx = -1e30f;
#pragma unroll
      for (int nf = 0; nf < 4; ++nf) {
        s[nf][r] *= 0.125f;
        mx = fmaxf(mx, s[nf][r]);
      }
#pragma unroll
      for (int off = 1; off < 16; off <<= 1) mx = fmaxf(mx, __shfl_xor(mx, off));
      float mnew = fmaxf(m_i[r], mx);
      float sf = __expf(m_i[r] - mnew);
      m_i[r] = mnew;
      l_i[r] *= sf;
#pragma unroll
      for (int df = 0; df < 4; ++df) ctx[df][r] *= sf;
      float rs = 0.0f;
#pragma unroll
      for (int nf = 0; nf < 4; ++nf) {
        float p = __expf(s[nf][r] - mnew);
        s[nf][r] = p;
        rs += p;
      }
#pragma unroll
      for (int off = 1; off < 16; off <<= 1) rs += __shfl_xor(rs, off);
      l_i[r] += rs;
    }

    // write P (bf16) to this wave's LDS tile: Ps[q][kk]
#pragma unroll
    for (int nf = 0; nf < 4; ++nf)
#pragma unroll
      for (int r = 0; r < 4; ++r)
        Ps[wave * 16 * 72 + (kg * 4 + r) * 72 + nf * 16 + lr] = f2bf(s[nf][r]);
    __syncthreads();

    // ctx += P @ V
    bf16x8 pf0 = *reinterpret_cast<const bf16x8*>(&Ps[wave * 16 * 72 + lr * 72 + kg * 8]);
    bf16x8 pf1 = *reinterpret_cast<const bf16x8*>(&Ps[wave * 16 * 72 + lr * 72 + 32 + kg * 8]);
#pragma unroll
    for (int df = 0; df < 4; ++df) {
      bf16x8 vf0 = *reinterpret_cast<const bf16x8*>(&Vt[(df * 16 + lr) * 72 + kg * 8]);
      bf16x8 vf1 = *reinterpret_cast<const bf16x8*>(&Vt[(df * 16 + lr) * 72 + 32 + kg * 8]);
      ctx[df] = __builtin_amdgcn_mfma_f32_16x16x32_bf16(pf0, vf0, ctx[df], 0, 0, 0);
      ctx[df] = __builtin_amdgcn_mfma_f32_16x16x32_bf16(pf1, vf1, ctx[df], 0, 0, 0);
    }
  }

  // normalize + store
#pragma unroll
  for (int df = 0; df < 4; ++df)
#pragma unroll
    for (int r = 0; r < 4; ++r) {
      float v = ctx[df][r] / l_i[r];
      O[(rowbase + qt * 64 + wave * 16 + kg * 4 + r) * H_ + hcol + df * 16 + lr] = f2bf(v);
    }
}

// ---------------- fused residual add + LayerNorm ----------------
// one block (256 thr) per row of 1024
template<int IN2_BF16, int WRITE_BF16>
__global__ __launch_bounds__(256) void add_ln(const float* __restrict__ X,
                                              const void* __restrict__ Y,
                                              const float* __restrict__ g,
                                              const float* __restrict__ beta,
                                              float* __restrict__ outF,
                                              unsigned short* __restrict__ outB) {
  const int row = blockIdx.x;
  const int tid = threadIdx.x;
  const int wave = tid >> 6, lane = tid & 63;
  __shared__ float red[8];

  float vals[4];
  float s = 0.0f, s2 = 0.0f;
#pragma unroll
  for (int i = 0; i < 4; ++i) {
    int c = i * 256 + tid;
    float v = X[(size_t)row * H_ + c];
    if (IN2_BF16) v += bf2f(reinterpret_cast<const unsigned short*>(Y)[(size_t)row * H_ + c]);
    else          v += reinterpret_cast<const float*>(Y)[(size_t)row * H_ + c];
    vals[i] = v;
    s += v;
    s2 += v * v;
  }
#pragma unroll
  for (int off = 32; off; off >>= 1) { s += __shfl_xor(s, off); s2 += __shfl_xor(s2, off); }
  if (lane == 0) { red[wave * 2] = s; red[wave * 2 + 1] = s2; }
  __syncthreads();
  s  = red[0] + red[2] + red[4] + red[6];
  s2 = red[1] + red[3] + red[5] + red[7];
  float mean = s * (1.0f / H_);
  float var  = s2 * (1.0f / H_) - mean * mean;
  float rstd = rsqrtf(var + 1e-5f);
#pragma unroll
  for (int i = 0; i < 4; ++i) {
    int c = i * 256 + tid;
    float v = (vals[i] - mean) * rstd * g[c] + beta[c];
    if (outF) outF[(size_t)row * H_ + c] = v;
    if (WRITE_BF16) outB[(size_t)row * H_ + c] = f2bf(v);
  }
}

// ---------------- orchestration ----------------
extern "C" void kernel_launch(void* const* d_in, const int* in_sizes, int n_in,
                              void* d_out, int out_size, void* d_ws, size_t ws_size,
                              hipStream_t stream) {
  const float* x  = (const float*)d_in[0];
  const float* Wq = (const float*)d_in[1];
  const float* bq = (const float*)d_in[2];
  const float* Wk = (const float*)d_in[3];
  const float* bk = (const float*)d_in[4];
  const float* Wv = (const float*)d_in[5];
  const float* bv = (const float*)d_in[6];
  const float* Wi = (const float*)d_in[7];
  const float* bi = (const float*)d_in[8];
  const float* Wo = (const float*)d_in[9];
  const float* bo = (const float*)d_in[10];
  const float* g1 = (const float*)d_in[11];
  const float* b1 = (const float*)d_in[12];
  const float* g2 = (const float*)d_in[13];
  const float* b2 = (const float*)d_in[14];

  unsigned char* ws = (unsigned char*)d_ws;
  size_t off = 0;
  auto alloc = [&](size_t bytes) { size_t o = off; off += (bytes + 255) & ~(size_t)255; return o; };

  unsigned short* xb  = (unsigned short*)(ws + alloc((size_t)M_ * H_ * 2));
  unsigned short* Wqb = (unsigned short*)(ws + alloc((size_t)H_ * H_ * 2));
  unsigned short* Wkb = (unsigned short*)(ws + alloc((size_t)H_ * H_ * 2));
  unsigned short* Wvb = (unsigned short*)(ws + alloc((size_t)H_ * H_ * 2));
  unsigned short* Wib = (unsigned short*)(ws + alloc((size_t)H_ * FF_ * 2));
  unsigned short* Wob = (unsigned short*)(ws + alloc((size_t)FF_ * H_ * 2));
  unsigned short* qb  = (unsigned short*)(ws + alloc((size_t)M_ * H_ * 2));
  unsigned short* kb  = (unsigned short*)(ws + alloc((size_t)M_ * H_ * 2));
  unsigned short* vb  = (unsigned short*)(ws + alloc((size_t)M_ * H_ * 2));
  unsigned short* ao  = (unsigned short*)(ws + alloc((size_t)M_ * H_ * 2));
  float*          hf  = (float*)(ws + alloc((size_t)M_ * H_ * 4));
  unsigned short* hb  = (unsigned short*)(ws + alloc((size_t)M_ * H_ * 2));
  unsigned short* f1  = (unsigned short*)(ws + alloc((size_t)M_ * FF_ * 2));
  float*          f2  = (float*)(ws + alloc((size_t)M_ * H_ * 4));

  auto cast = [&](const float* src, unsigned short* dst, size_t n) {
    int n4 = (int)(n / 4);
    cast_f32_bf16<<<(n4 + 255) / 256, 256, 0, stream>>>(src, dst, n4);
  };
  cast(x,  xb,  (size_t)M_ * H_);
  cast(Wq, Wqb, (size_t)H_ * H_);
  cast(Wk, Wkb, (size_t)H_ * H_);
  cast(Wv, Wvb, (size_t)H_ * H_);
  cast(Wi, Wib, (size_t)H_ * FF_);
  cast(Wo, Wob, (size_t)FF_ * H_);

  // QKV projections
  gemm_bf16<0, 0><<<dim3(M_ / 128, H_ / 128), 256, 0, stream>>>(xb, Wqb, bq, qb, M_, H_, H_);
  gemm_bf16<0, 0><<<dim3(M_ / 128, H_ / 128), 256, 0, stream>>>(xb, Wkb, bk, kb, M_, H_, H_);
  gemm_bf16<0, 0><<<dim3(M_ / 128, H_ / 128), 256, 0, stream>>>(xb, Wvb, bv, vb, M_, H_, H_);

  // attention
  attn_fwd<<<dim3(S_ / 64, B_ * NH_), 256, 0, stream>>>(qb, kb, vb, ao);

  // h = LN(x + attn)
  add_ln<1, 1><<<M_, 256, 0, stream>>>(x, ao, g1, b1, hf, hb);

  // FFN
  gemm_bf16<1, 0><<<dim3(M_ / 128, FF_ / 128), 256, 0, stream>>>(hb, Wib, bi, f1, M_, FF_, H_);
  gemm_bf16<0, 1><<<dim3(M_ / 128, H_ / 128), 256, 0, stream>>>(f1, Wob, bo, f2, M_, H_, FF_);

  // out = LN(h + ffn)
  add_ln<0, 0><<<M_, 256, 0, stream>>>(hf, f2, g2, b2, (float*)d_out, nullptr);
}

// Round 2
// 582.565 us; speedup vs baseline: 2.1945x; 2.1945x over previous
//
#include <hip/hip_runtime.h>

// ---- problem constants ----
#define B_  4
#define S_  2048
#define H_  1024
#define NH_ 16
#define HD_ 64
#define FF_ 4096
#define M_  (B_*S_)   // 8192 rows

typedef __bf16 bf16x8 __attribute__((ext_vector_type(8)));
typedef float  f32x4  __attribute__((ext_vector_type(4)));
typedef unsigned short ushort8v __attribute__((ext_vector_type(8)));
typedef unsigned short ushort4v __attribute__((ext_vector_type(4)));

typedef __attribute__((address_space(1))) void GVOID;
typedef __attribute__((address_space(3))) void LVOID;

__device__ __forceinline__ void g2l16(const void* g, void* l) {
  // async global->LDS, 16B per lane; LDS dest = wave-uniform base + lane*16
  __builtin_amdgcn_global_load_lds((GVOID*)g, (LVOID*)l, 16, 0, 0);
}

__device__ __forceinline__ unsigned short f2bf(float f) {
  unsigned int u = __float_as_uint(f);
  u += 0x7fffu + ((u >> 16) & 1u);   // round-to-nearest-even
  return (unsigned short)(u >> 16);
}
__device__ __forceinline__ float bf2f(unsigned short h) {
  return __uint_as_float(((unsigned int)h) << 16);
}

// ---------------- cast fp32 -> bf16 ----------------
__global__ __launch_bounds__(256) void cast_f32_bf16(const float* __restrict__ in,
                                                     unsigned short* __restrict__ out,
                                                     int n4) {
  int i = blockIdx.x * 256 + threadIdx.x;
  if (i >= n4) return;
  float4 v = reinterpret_cast<const float4*>(in)[i];
  ushort4v o;
  o[0] = f2bf(v.x); o[1] = f2bf(v.y); o[2] = f2bf(v.z); o[3] = f2bf(v.w);
  reinterpret_cast<ushort4v*>(out)[i] = o;
}

// ---------------- transpose + cast: W[R][C] f32 -> WT[C][R] bf16 ----------------
__global__ __launch_bounds__(256) void transpose_cast(const float* __restrict__ in,
                                                      unsigned short* __restrict__ out,
                                                      int R, int C) {
  __shared__ float t[32][33];
  const int bx = blockIdx.x * 32;  // col tile of in (row tile of out)
  const int by = blockIdx.y * 32;  // row tile of in
  const int tx = threadIdx.x & 31, ty = threadIdx.x >> 5;  // ty 0..7
#pragma unroll
  for (int i = 0; i < 32; i += 8)
    t[ty + i][tx] = in[(size_t)(by + ty + i) * C + bx + tx];
  __syncthreads();
#pragma unroll
  for (int i = 0; i < 32; i += 8)
    out[(size_t)(bx + ty + i) * R + by + tx] = f2bf(t[tx][ty + i]);
}

// ---------------- TN GEMM: C[M,N] = act(A[M,K] @ Bt[N,K]^T + bias) ----------------
// Both operands row-major [rows][K]. 128x128 tile, BK=32, 4 waves (2x2 of 64x64).
// Staging via global_load_lds width=16, XOR-swizzled (elem ^= ((row>>1)&3)<<3).
// ACT: 0 none, 1 exact gelu. OUT_F32: 1 float out, 0 bf16. BIAS_ROW: bias by row.
template<int ACT, int OUT_F32, int BIAS_ROW>
__global__ __launch_bounds__(256) void gemm_tn(const unsigned short* __restrict__ A,
                                               const unsigned short* __restrict__ Bt,
                                               const float* __restrict__ bias,
                                               void* __restrict__ C,
                                               int M, int N, int K) {
  __shared__ unsigned short As[128 * 32];
  __shared__ unsigned short Bs[128 * 32];

  const int tid  = threadIdx.x;
  const int wave = tid >> 6;
  const int lane = tid & 63;
  const int kg   = lane >> 4;      // 0..3
  const int lr   = lane & 15;      // 0..15
  const int m0 = blockIdx.x * 128;
  const int n0 = blockIdx.y * 128;
  const int wr = (wave >> 1) * 64;
  const int wc = (wave & 1) * 64;

  // staging geometry: chunk = wave*2+i covers rows chunk*16 .. +15, 32 k each
  const int r0 = (wave * 2 + 0) * 16 + (lane >> 2);
  const int r1 = (wave * 2 + 1) * 16 + (lane >> 2);
  const int ke = ((lane & 3) * 8) ^ (((lane >> 3) & 3) << 3);  // swizzled k-elem
  unsigned short* ldsA0 = &As[(wave * 2 + 0) * 512];
  unsigned short* ldsA1 = &As[(wave * 2 + 1) * 512];
  unsigned short* ldsB0 = &Bs[(wave * 2 + 0) * 512];
  unsigned short* ldsB1 = &Bs[(wave * 2 + 1) * 512];
  const int swz = ((lr >> 1) & 3) << 3;  // fragment-read swizzle

  f32x4 acc[4][4] = {};

  for (int k0 = 0; k0 < K; k0 += 32) {
    __syncthreads();
    g2l16(&A [(size_t)(m0 + r0) * K + k0 + ke], ldsA0);
    g2l16(&A [(size_t)(m0 + r1) * K + k0 + ke], ldsA1);
    g2l16(&Bt[(size_t)(n0 + r0) * K + k0 + ke], ldsB0);
    g2l16(&Bt[(size_t)(n0 + r1) * K + k0 + ke], ldsB1);
    __syncthreads();

    bf16x8 af[4], bfr[4];
#pragma unroll
    for (int mi = 0; mi < 4; ++mi)
      af[mi] = *reinterpret_cast<const bf16x8*>(&As[(wr + mi * 16 + lr) * 32 + ((kg * 8) ^ swz)]);
#pragma unroll
    for (int ni = 0; ni < 4; ++ni)
      bfr[ni] = *reinterpret_cast<const bf16x8*>(&Bs[(wc + ni * 16 + lr) * 32 + ((kg * 8) ^ swz)]);
#pragma unroll
    for (int mi = 0; mi < 4; ++mi)
#pragma unroll
      for (int ni = 0; ni < 4; ++ni)
        acc[mi][ni] = __builtin_amdgcn_mfma_f32_16x16x32_bf16(af[mi], bfr[ni], acc[mi][ni], 0, 0, 0);
  }

  // epilogue: D row = (lane>>4)*4 + reg, col = lane&15
#pragma unroll
  for (int mi = 0; mi < 4; ++mi) {
#pragma unroll
    for (int ni = 0; ni < 4; ++ni) {
      int col = n0 + wc + ni * 16 + lr;
      float bc = (!BIAS_ROW && bias) ? bias[col] : 0.0f;
#pragma unroll
      for (int r = 0; r < 4; ++r) {
        int row = m0 + wr + mi * 16 + kg * 4 + r;
        float v = acc[mi][ni][r] + (BIAS_ROW ? bias[row] : bc);
        if (ACT == 1) v = 0.5f * v * (1.0f + erff(v * 0.70710678118f));
        if (OUT_F32) reinterpret_cast<float*>(C)[(size_t)row * N + col] = v;
        else reinterpret_cast<unsigned short*>(C)[(size_t)row * N + col] = f2bf(v);
      }
    }
  }
}

// ---------------- flash attention ----------------
// grid: (S/64, B*NH). 4 waves/block, each wave owns 16 q rows.
// K staged row-major [kk][64d], V^T staged [d][64kk], both via global_load_lds
// with XOR swizzle (elem ^= (row&7)<<3 on 128B rows).
__global__ __launch_bounds__(256) void attn_fwd(const unsigned short* __restrict__ Q,
                                                const unsigned short* __restrict__ Kb,
                                                const unsigned short* __restrict__ VT,
                                                unsigned short* __restrict__ O) {
  __shared__ unsigned short Ks[64 * 64];
  __shared__ unsigned short Vs[64 * 64];
  __shared__ unsigned short Ps[4 * 16 * 72];

  const int tid  = threadIdx.x;
  const int wave = tid >> 6;
  const int lane = tid & 63;
  const int kg   = lane >> 4;
  const int lr   = lane & 15;
  const int qt = blockIdx.x;            // 0..31
  const int bh = blockIdx.y;            // 0..63
  const int b  = bh >> 4;
  const int h  = bh & 15;
  const size_t rowbase = (size_t)b * S_;
  const int hcol = h * 64;
  const int bcol0 = b * S_;             // col base in VT
  const int q0 = qt * 64 + wave * 16;

  // staging geometry: chunk = wave*2+i covers 8 rows x 64 elems
  const int rT0 = (wave * 2 + 0) * 8 + (lane >> 3);
  const int rT1 = (wave * 2 + 1) * 8 + (lane >> 3);
  const int ce  = ((lane & 7) * 8) ^ (((lane >> 3) & 7) << 3);
  unsigned short* ldsK0 = &Ks[(wave * 2 + 0) * 512];
  unsigned short* ldsK1 = &Ks[(wave * 2 + 1) * 512];
  unsigned short* ldsV0 = &Vs[(wave * 2 + 0) * 512];
  unsigned short* ldsV1 = &Vs[(wave * 2 + 1) * 512];
  const int fswz = (lr & 7) << 3;       // fragment-read swizzle

  // Q fragments in registers for the whole kernel
  bf16x8 qf[2];
#pragma unroll
  for (int d = 0; d < 2; ++d)
    qf[d] = *reinterpret_cast<const bf16x8*>(&Q[(rowbase + q0 + lr) * H_ + hcol + d * 32 + kg * 8]);

  f32x4 ctx[4] = {};
  float m_i[4], l_i[4];
#pragma unroll
  for (int r = 0; r < 4; ++r) { m_i[r] = -1e30f; l_i[r] = 0.0f; }

  for (int kt = 0; kt < S_ / 64; ++kt) {
    __syncthreads();   // all waves done reading prev K/V
    g2l16(&Kb[(rowbase + kt * 64 + rT0) * H_ + hcol + ce], ldsK0);
    g2l16(&Kb[(rowbase + kt * 64 + rT1) * H_ + hcol + ce], ldsK1);
    g2l16(&VT[(size_t)(hcol + rT0) * M_ + bcol0 + kt * 64 + ce], ldsV0);
    g2l16(&VT[(size_t)(hcol + rT1) * M_ + bcol0 + kt * 64 + ce], ldsV1);
    __syncthreads();   // tiles ready

    // S = Q K^T / 8
    f32x4 s[4];
#pragma unroll
    for (int nf = 0; nf < 4; ++nf) {
      int row = nf * 16 + lr;
      bf16x8 kf0 = *reinterpret_cast<const bf16x8*>(&Ks[row * 64 + ((kg * 8) ^ fswz)]);
      bf16x8 kf1 = *reinterpret_cast<const bf16x8*>(&Ks[row * 64 + ((32 + kg * 8) ^ fswz)]);
      f32x4 z = {0.0f, 0.0f, 0.0f, 0.0f};
      z = __builtin_amdgcn_mfma_f32_16x16x32_bf16(qf[0], kf0, z, 0, 0, 0);
      z = __builtin_amdgcn_mfma_f32_16x16x32_bf16(qf[1], kf1, z, 0, 0, 0);
      s[nf] = z;
    }

    // online softmax per q-row (row = kg*4 + r, replicated over 16 lanes)
#pragma unroll
    for (int r = 0; r < 4; ++r) {
      float mx = -1e30f;
#pragma unroll
      for (int nf = 0; nf < 4; ++nf) {
        s[nf][r] *= 0.125f;
        mx = fmaxf(mx, s[nf][r]);
      }
#pragma unroll
      for (int off = 1; off < 16; off <<= 1) mx = fmaxf(mx, __shfl_xor(mx, off));
      float mnew = fmaxf(m_i[r], mx);
      float sf = __expf(m_i[r] - mnew);
      m_i[r] = mnew;
      l_i[r] *= sf;
#pragma unroll
      for (int df = 0; df < 4; ++df) ctx[df][r] *= sf;
      float rs = 0.0f;
#pragma unroll
      for (int nf = 0; nf < 4; ++nf) {
        float p = __expf(s[nf][r] - mnew);
        s[nf][r] = p;
        rs += p;
      }
#pragma unroll
      for (int off = 1; off < 16; off <<= 1) rs += __shfl_xor(rs, off);
      l_i[r] += rs;
    }

    // write P (bf16) to this wave's private LDS tile: Ps[q][kk]
#pragma unroll
    for (int nf = 0; nf < 4; ++nf)
#pragma unroll
      for (int r = 0; r < 4; ++r)
        Ps[wave * 16 * 72 + (kg * 4 + r) * 72 + nf * 16 + lr] = f2bf(s[nf][r]);

    // ctx += P @ V  (wave-private Ps; compiler inserts lgkm waits)
    bf16x8 pf0 = *reinterpret_cast<const bf16x8*>(&Ps[wave * 16 * 72 + lr * 72 + kg * 8]);
    bf16x8 pf1 = *reinterpret_cast<const bf16x8*>(&Ps[wave * 16 * 72 + lr * 72 + 32 + kg * 8]);
#pragma unroll
    for (int df = 0; df < 4; ++df) {
      int row = df * 16 + lr;
      bf16x8 vf0 = *reinterpret_cast<const bf16x8*>(&Vs[row * 64 + ((kg * 8) ^ fswz)]);
      bf16x8 vf1 = *reinterpret_cast<const bf16x8*>(&Vs[row * 64 + ((32 + kg * 8) ^ fswz)]);
      ctx[df] = __builtin_amdgcn_mfma_f32_16x16x32_bf16(pf0, vf0, ctx[df], 0, 0, 0);
      ctx[df] = __builtin_amdgcn_mfma_f32_16x16x32_bf16(pf1, vf1, ctx[df], 0, 0, 0);
    }
  }

  // normalize + store
#pragma unroll
  for (int df = 0; df < 4; ++df)
#pragma unroll
    for (int r = 0; r < 4; ++r) {
      float v = ctx[df][r] / l_i[r];
      O[(rowbase + qt * 64 + wave * 16 + kg * 4 + r) * H_ + hcol + df * 16 + lr] = f2bf(v);
    }
}

// ---------------- fused residual add + LayerNorm ----------------
template<int IN2_BF16, int WRITE_BF16>
__global__ __launch_bounds__(256) void add_ln(const float* __restrict__ X,
                                              const void* __restrict__ Y,
                                              const float* __restrict__ g,
                                              const float* __restrict__ beta,
                                              float* __restrict__ outF,
                                              unsigned short* __restrict__ outB) {
  const int row = blockIdx.x;
  const int tid = threadIdx.x;
  const int wave = tid >> 6, lane = tid & 63;
  __shared__ float red[8];

  float vals[4];
  float s = 0.0f, s2 = 0.0f;
#pragma unroll
  for (int i = 0; i < 4; ++i) {
    int c = i * 256 + tid;
    float v = X[(size_t)row * H_ + c];
    if (IN2_BF16) v += bf2f(reinterpret_cast<const unsigned short*>(Y)[(size_t)row * H_ + c]);
    else          v += reinterpret_cast<const float*>(Y)[(size_t)row * H_ + c];
    vals[i] = v;
    s += v;
    s2 += v * v;
  }
#pragma unroll
  for (int off = 32; off; off >>= 1) { s += __shfl_xor(s, off); s2 += __shfl_xor(s2, off); }
  if (lane == 0) { red[wave * 2] = s; red[wave * 2 + 1] = s2; }
  __syncthreads();
  s  = red[0] + red[2] + red[4] + red[6];
  s2 = red[1] + red[3] + red[5] + red[7];
  float mean = s * (1.0f / H_);
  float var  = s2 * (1.0f / H_) - mean * mean;
  float rstd = rsqrtf(var + 1e-5f);
#pragma unroll
  for (int i = 0; i < 4; ++i) {
    int c = i * 256 + tid;
    float v = (vals[i] - mean) * rstd * g[c] + beta[c];
    if (outF) outF[(size_t)row * H_ + c] = v;
    if (WRITE_BF16) outB[(size_t)row * H_ + c] = f2bf(v);
  }
}

// ---------------- orchestration ----------------
extern "C" void kernel_launch(void* const* d_in, const int* in_sizes, int n_in,
                              void* d_out, int out_size, void* d_ws, size_t ws_size,
                              hipStream_t stream) {
  const float* x  = (const float*)d_in[0];
  const float* Wq = (const float*)d_in[1];
  const float* bq = (const float*)d_in[2];
  const float* Wk = (const float*)d_in[3];
  const float* bk = (const float*)d_in[4];
  const float* Wv = (const float*)d_in[5];
  const float* bv = (const float*)d_in[6];
  const float* Wi = (const float*)d_in[7];
  const float* bi = (const float*)d_in[8];
  const float* Wo = (const float*)d_in[9];
  const float* bo = (const float*)d_in[10];
  const float* g1 = (const float*)d_in[11];
  const float* b1 = (const float*)d_in[12];
  const float* g2 = (const float*)d_in[13];
  const float* b2 = (const float*)d_in[14];

  unsigned char* ws = (unsigned char*)d_ws;
  size_t off = 0;
  auto alloc = [&](size_t bytes) { size_t o = off; off += (bytes + 255) & ~(size_t)255; return o; };

  unsigned short* xb  = (unsigned short*)(ws + alloc((size_t)M_ * H_ * 2));
  unsigned short* WqT = (unsigned short*)(ws + alloc((size_t)H_ * H_ * 2));
  unsigned short* WkT = (unsigned short*)(ws + alloc((size_t)H_ * H_ * 2));
  unsigned short* WvT = (unsigned short*)(ws + alloc((size_t)H_ * H_ * 2));
  unsigned short* WiT = (unsigned short*)(ws + alloc((size_t)H_ * FF_ * 2));
  unsigned short* WoT = (unsigned short*)(ws + alloc((size_t)FF_ * H_ * 2));
  unsigned short* qb  = (unsigned short*)(ws + alloc((size_t)M_ * H_ * 2));
  unsigned short* kb  = (unsigned short*)(ws + alloc((size_t)M_ * H_ * 2));
  unsigned short* vt  = (unsigned short*)(ws + alloc((size_t)M_ * H_ * 2));  // V^T [H][M]
  unsigned short* ao  = (unsigned short*)(ws + alloc((size_t)M_ * H_ * 2));
  float*          hf  = (float*)(ws + alloc((size_t)M_ * H_ * 4));
  unsigned short* hb  = (unsigned short*)(ws + alloc((size_t)M_ * H_ * 2));
  unsigned short* f1  = (unsigned short*)(ws + alloc((size_t)M_ * FF_ * 2));
  float*          f2  = (float*)(ws + alloc((size_t)M_ * H_ * 4));

  // cast x; transpose-cast all weights to [N][K] bf16
  {
    int n4 = (int)((size_t)M_ * H_ / 4);
    cast_f32_bf16<<<(n4 + 255) / 256, 256, 0, stream>>>(x, xb, n4);
  }
  transpose_cast<<<dim3(H_ / 32, H_ / 32), 256, 0, stream>>>(Wq, WqT, H_, H_);
  transpose_cast<<<dim3(H_ / 32, H_ / 32), 256, 0, stream>>>(Wk, WkT, H_, H_);
  transpose_cast<<<dim3(H_ / 32, H_ / 32), 256, 0, stream>>>(Wv, WvT, H_, H_);
  transpose_cast<<<dim3(FF_ / 32, H_ / 32), 256, 0, stream>>>(Wi, WiT, H_, FF_);
  transpose_cast<<<dim3(H_ / 32, FF_ / 32), 256, 0, stream>>>(Wo, WoT, FF_, H_);

  // Q, K projections: [M,H] = xb @ WqT^T
  gemm_tn<0, 0, 0><<<dim3(M_ / 128, H_ / 128), 256, 0, stream>>>(xb, WqT, bq, qb, M_, H_, H_);
  gemm_tn<0, 0, 0><<<dim3(M_ / 128, H_ / 128), 256, 0, stream>>>(xb, WkT, bk, kb, M_, H_, H_);
  // V^T: [H,M] = WvT @ xb^T  (bias indexed by row)
  gemm_tn<0, 0, 1><<<dim3(H_ / 128, M_ / 128), 256, 0, stream>>>(WvT, xb, bv, vt, H_, M_, H_);

  // attention
  attn_fwd<<<dim3(S_ / 64, B_ * NH_), 256, 0, stream>>>(qb, kb, vt, ao);

  // h = LN(x + attn)
  add_ln<1, 1><<<M_, 256, 0, stream>>>(x, ao, g1, b1, hf, hb);

  // FFN
  gemm_tn<1, 0, 0><<<dim3(M_ / 128, FF_ / 128), 256, 0, stream>>>(hb, WiT, bi, f1, M_, FF_, H_);
  gemm_tn<0, 1, 0><<<dim3(M_ / 128, H_ / 128), 256, 0, stream>>>(f1, WoT, bo, f2, M_, H_, FF_);

  // out = LN(h + ffn)
  add_ln<0, 0><<<M_, 256, 0, stream>>>(hf, f2, g2, b2, (float*)d_out, nullptr);
}

// Round 3
// 551.076 us; speedup vs baseline: 2.3199x; 1.0571x over previous
//
#include <hip/hip_runtime.h>

// ---- problem constants ----
#define B_  4
#define S_  2048
#define H_  1024
#define NH_ 16
#define HD_ 64
#define FF_ 4096
#define M_  (B_*S_)   // 8192 rows

typedef __bf16 bf16x8 __attribute__((ext_vector_type(8)));
typedef float  f32x4  __attribute__((ext_vector_type(4)));
typedef unsigned short ushort8v __attribute__((ext_vector_type(8)));
typedef unsigned short ushort4v __attribute__((ext_vector_type(4)));

typedef __attribute__((address_space(1))) void GVOID;
typedef __attribute__((address_space(3))) void LVOID;

__device__ __forceinline__ void g2l16(const void* g, void* l) {
  __builtin_amdgcn_global_load_lds((GVOID*)g, (LVOID*)l, 16, 0, 0);
}

__device__ __forceinline__ unsigned short f2bf(float f) {
  unsigned int u = __float_as_uint(f);
  u += 0x7fffu + ((u >> 16) & 1u);
  return (unsigned short)(u >> 16);
}
__device__ __forceinline__ float bf2f(unsigned short h) {
  return __uint_as_float(((unsigned int)h) << 16);
}

// bijective XCD swizzle for grids with nwg % 8 == 0
__device__ __forceinline__ void xcd_swz(int& bx, int& by) {
  int gx = gridDim.x;
  int flat = by * gx + bx;
  int cpx = (gx * gridDim.y) >> 3;
  int swz = (flat & 7) * cpx + (flat >> 3);
  bx = swz % gx;
  by = swz / gx;
}

// ---------------- cast fp32 -> bf16 ----------------
__global__ __launch_bounds__(256) void cast_f32_bf16(const float* __restrict__ in,
                                                     unsigned short* __restrict__ out,
                                                     int n4) {
  int i = blockIdx.x * 256 + threadIdx.x;
  if (i >= n4) return;
  float4 v = reinterpret_cast<const float4*>(in)[i];
  ushort4v o;
  o[0] = f2bf(v.x); o[1] = f2bf(v.y); o[2] = f2bf(v.z); o[3] = f2bf(v.w);
  reinterpret_cast<ushort4v*>(out)[i] = o;
}

// ---------------- transpose + cast: W[R][C] f32 -> WT[C][R] bf16 ----------------
__global__ __launch_bounds__(256) void transpose_cast(const float* __restrict__ in,
                                                      unsigned short* __restrict__ out,
                                                      int R, int C) {
  __shared__ float t[32][33];
  const int bx = blockIdx.x * 32;
  const int by = blockIdx.y * 32;
  const int tx = threadIdx.x & 31, ty = threadIdx.x >> 5;
#pragma unroll
  for (int i = 0; i < 32; i += 8)
    t[ty + i][tx] = in[(size_t)(by + ty + i) * C + bx + tx];
  __syncthreads();
#pragma unroll
  for (int i = 0; i < 32; i += 8)
    out[(size_t)(bx + ty + i) * R + by + tx] = f2bf(t[tx][ty + i]);
}

// ---------------- TN GEMM: C[M,N] = act(A[M,K] @ Bt[N,K]^T + bias) * scale ------
template<int ACT, int OUT_F32, int BIAS_ROW>
__global__ __launch_bounds__(256) void gemm_tn(const unsigned short* __restrict__ A,
                                               const unsigned short* __restrict__ Bt,
                                               const float* __restrict__ bias,
                                               void* __restrict__ C,
                                               int M, int N, int K, float scale) {
  __shared__ unsigned short As[128 * 32];
  __shared__ unsigned short Bs[128 * 32];

  const int tid  = threadIdx.x;
  const int wave = tid >> 6;
  const int lane = tid & 63;
  const int kg   = lane >> 4;
  const int lr   = lane & 15;
  int bx = blockIdx.x, by = blockIdx.y;
  xcd_swz(bx, by);
  const int m0 = bx * 128;
  const int n0 = by * 128;
  const int wr = (wave >> 1) * 64;
  const int wc = (wave & 1) * 64;

  const int r0 = (wave * 2 + 0) * 16 + (lane >> 2);
  const int r1 = (wave * 2 + 1) * 16 + (lane >> 2);
  const int ke = ((lane & 3) * 8) ^ (((lane >> 3) & 3) << 3);
  unsigned short* ldsA0 = &As[(wave * 2 + 0) * 512];
  unsigned short* ldsA1 = &As[(wave * 2 + 1) * 512];
  unsigned short* ldsB0 = &Bs[(wave * 2 + 0) * 512];
  unsigned short* ldsB1 = &Bs[(wave * 2 + 1) * 512];
  const int swz = ((lr >> 1) & 3) << 3;

  f32x4 acc[4][4] = {};

  for (int k0 = 0; k0 < K; k0 += 32) {
    __syncthreads();
    g2l16(&A [(size_t)(m0 + r0) * K + k0 + ke], ldsA0);
    g2l16(&A [(size_t)(m0 + r1) * K + k0 + ke], ldsA1);
    g2l16(&Bt[(size_t)(n0 + r0) * K + k0 + ke], ldsB0);
    g2l16(&Bt[(size_t)(n0 + r1) * K + k0 + ke], ldsB1);
    __syncthreads();

    bf16x8 af[4], bfr[4];
#pragma unroll
    for (int mi = 0; mi < 4; ++mi)
      af[mi] = *reinterpret_cast<const bf16x8*>(&As[(wr + mi * 16 + lr) * 32 + ((kg * 8) ^ swz)]);
#pragma unroll
    for (int ni = 0; ni < 4; ++ni)
      bfr[ni] = *reinterpret_cast<const bf16x8*>(&Bs[(wc + ni * 16 + lr) * 32 + ((kg * 8) ^ swz)]);
#pragma unroll
    for (int mi = 0; mi < 4; ++mi)
#pragma unroll
      for (int ni = 0; ni < 4; ++ni)
        acc[mi][ni] = __builtin_amdgcn_mfma_f32_16x16x32_bf16(af[mi], bfr[ni], acc[mi][ni], 0, 0, 0);
  }

#pragma unroll
  for (int mi = 0; mi < 4; ++mi) {
#pragma unroll
    for (int ni = 0; ni < 4; ++ni) {
      int col = n0 + wc + ni * 16 + lr;
      float bc = (!BIAS_ROW && bias) ? bias[col] : 0.0f;
#pragma unroll
      for (int r = 0; r < 4; ++r) {
        int row = m0 + wr + mi * 16 + kg * 4 + r;
        float v = acc[mi][ni][r] + (BIAS_ROW ? bias[row] : bc);
        if (ACT == 1) v = 0.5f * v * (1.0f + erff(v * 0.70710678118f));
        v *= scale;
        if (OUT_F32) reinterpret_cast<float*>(C)[(size_t)row * N + col] = v;
        else reinterpret_cast<unsigned short*>(C)[(size_t)row * N + col] = f2bf(v);
      }
    }
  }
}

// ---------------- flash attention ----------------
// grid: (S/128, B*NH). 4 waves/block, each wave owns 32 q rows (2 subtiles of 16).
// Q pre-scaled by log2e/8 (exp2-domain softmax). Double-buffered K/V staging.
// Wave-shared running max; row-sum via ones-MFMA (l = extra accumulator).
__global__ __launch_bounds__(256) void attn_fwd(const unsigned short* __restrict__ Q,
                                                const unsigned short* __restrict__ Kb,
                                                const unsigned short* __restrict__ VT,
                                                unsigned short* __restrict__ O) {
  __shared__ unsigned short Ks[2][64 * 64];
  __shared__ unsigned short Vs[2][64 * 64];
  __shared__ __bf16 Ps[4][32 * 72];

  const int tid  = threadIdx.x;
  const int wave = tid >> 6;
  const int lane = tid & 63;
  const int kg   = lane >> 4;
  const int lr   = lane & 15;
  int bx = blockIdx.x, by = blockIdx.y;
  xcd_swz(bx, by);
  const int b  = by >> 4;
  const int h  = by & 15;
  const size_t rowbase = (size_t)b * S_;
  const int hcol = h * 64;
  const int bcol0 = b * S_;
  const int q0 = bx * 128 + wave * 32;

  // staging geometry: per wave 2 chunks of 8 rows x 64 elems for each of K,V
  const int rT0 = (wave * 2 + 0) * 8 + (lane >> 3);
  const int rT1 = (wave * 2 + 1) * 8 + (lane >> 3);
  const int ce  = ((lane & 7) * 8) ^ (((lane >> 3) & 7) << 3);
  const int fswz = (lr & 7) << 3;

  // Q fragments (pre-scaled): [sub][khalf]
  bf16x8 qf[2][2];
#pragma unroll
  for (int sub = 0; sub < 2; ++sub)
#pragma unroll
    for (int d = 0; d < 2; ++d)
      qf[sub][d] = *reinterpret_cast<const bf16x8*>(
          &Q[(rowbase + q0 + sub * 16 + lr) * H_ + hcol + d * 32 + kg * 8]);

  bf16x8 ones;
#pragma unroll
  for (int i = 0; i < 8; ++i) ones[i] = (__bf16)1.0f;

  f32x4 ctx[2][4] = {};
  f32x4 lsum[2] = {};
  float m_w = -1e30f;

  auto stage = [&](int kt, int buf) {
    g2l16(&Kb[(rowbase + kt * 64 + rT0) * H_ + hcol + ce], &Ks[buf][(wave * 2 + 0) * 512]);
    g2l16(&Kb[(rowbase + kt * 64 + rT1) * H_ + hcol + ce], &Ks[buf][(wave * 2 + 1) * 512]);
    g2l16(&VT[(size_t)(hcol + rT0) * M_ + bcol0 + kt * 64 + ce], &Vs[buf][(wave * 2 + 0) * 512]);
    g2l16(&VT[(size_t)(hcol + rT1) * M_ + bcol0 + kt * 64 + ce], &Vs[buf][(wave * 2 + 1) * 512]);
  };

  stage(0, 0);
  __syncthreads();   // implicit vmcnt(0) drain

  const int NT = S_ / 64;
  for (int kt = 0; kt < NT; ++kt) {
    const int cur = kt & 1;
    if (kt + 1 < NT) stage(kt + 1, cur ^ 1);   // prefetch into other buffer

    // ---- QK^T (exp2-domain scores) ----
    f32x4 s0[4], s1[4];
#pragma unroll
    for (int nf = 0; nf < 4; ++nf) {
      int row = nf * 16 + lr;
      bf16x8 kf0 = *reinterpret_cast<const bf16x8*>(&Ks[cur][row * 64 + ((kg * 8) ^ fswz)]);
      bf16x8 kf1 = *reinterpret_cast<const bf16x8*>(&Ks[cur][row * 64 + ((32 + kg * 8) ^ fswz)]);
      f32x4 z0 = {0.f, 0.f, 0.f, 0.f}, z1 = {0.f, 0.f, 0.f, 0.f};
      z0 = __builtin_amdgcn_mfma_f32_16x16x32_bf16(qf[0][0], kf0, z0, 0, 0, 0);
      z0 = __builtin_amdgcn_mfma_f32_16x16x32_bf16(qf[0][1], kf1, z0, 0, 0, 0);
      z1 = __builtin_amdgcn_mfma_f32_16x16x32_bf16(qf[1][0], kf0, z1, 0, 0, 0);
      z1 = __builtin_amdgcn_mfma_f32_16x16x32_bf16(qf[1][1], kf1, z1, 0, 0, 0);
      s0[nf] = z0;
      s1[nf] = z1;
    }

    // ---- wave-shared max ----
    float mx = -1e30f;
#pragma unroll
    for (int nf = 0; nf < 4; ++nf)
#pragma unroll
      for (int r = 0; r < 4; ++r) {
        mx = fmaxf(mx, s0[nf][r]);
        mx = fmaxf(mx, s1[nf][r]);
      }
#pragma unroll
    for (int off = 1; off < 64; off <<= 1) mx = fmaxf(mx, __shfl_xor(mx, off));

    if (mx > m_w) {                      // wave-uniform branch
      float sf = exp2f(m_w - mx);
      m_w = mx;
#pragma unroll
      for (int sub = 0; sub < 2; ++sub) {
#pragma unroll
        for (int df = 0; df < 4; ++df)
#pragma unroll
          for (int r = 0; r < 4; ++r) ctx[sub][df][r] *= sf;
#pragma unroll
        for (int r = 0; r < 4; ++r) lsum[sub][r] *= sf;
      }
    }

    // ---- P = exp2(s - m), write bf16 to wave-private LDS ----
#pragma unroll
    for (int nf = 0; nf < 4; ++nf)
#pragma unroll
      for (int r = 0; r < 4; ++r) {
        Ps[wave][(0 * 16 + kg * 4 + r) * 72 + nf * 16 + lr] = (__bf16)exp2f(s0[nf][r] - m_w);
        Ps[wave][(1 * 16 + kg * 4 + r) * 72 + nf * 16 + lr] = (__bf16)exp2f(s1[nf][r] - m_w);
      }

    // ---- PV + row-sum via ones-MFMA ----
    bf16x8 p00 = *reinterpret_cast<const bf16x8*>(&Ps[wave][(0 * 16 + lr) * 72 + kg * 8]);
    bf16x8 p01 = *reinterpret_cast<const bf16x8*>(&Ps[wave][(0 * 16 + lr) * 72 + 32 + kg * 8]);
    bf16x8 p10 = *reinterpret_cast<const bf16x8*>(&Ps[wave][(1 * 16 + lr) * 72 + kg * 8]);
    bf16x8 p11 = *reinterpret_cast<const bf16x8*>(&Ps[wave][(1 * 16 + lr) * 72 + 32 + kg * 8]);
#pragma unroll
    for (int df = 0; df < 4; ++df) {
      int row = df * 16 + lr;
      bf16x8 vf0 = *reinterpret_cast<const bf16x8*>(&Vs[cur][row * 64 + ((kg * 8) ^ fswz)]);
      bf16x8 vf1 = *reinterpret_cast<const bf16x8*>(&Vs[cur][row * 64 + ((32 + kg * 8) ^ fswz)]);
      ctx[0][df] = __builtin_amdgcn_mfma_f32_16x16x32_bf16(p00, vf0, ctx[0][df], 0, 0, 0);
      ctx[0][df] = __builtin_amdgcn_mfma_f32_16x16x32_bf16(p01, vf1, ctx[0][df], 0, 0, 0);
      ctx[1][df] = __builtin_amdgcn_mfma_f32_16x16x32_bf16(p10, vf0, ctx[1][df], 0, 0, 0);
      ctx[1][df] = __builtin_amdgcn_mfma_f32_16x16x32_bf16(p11, vf1, ctx[1][df], 0, 0, 0);
    }
    lsum[0] = __builtin_amdgcn_mfma_f32_16x16x32_bf16(p00, ones, lsum[0], 0, 0, 0);
    lsum[0] = __builtin_amdgcn_mfma_f32_16x16x32_bf16(p01, ones, lsum[0], 0, 0, 0);
    lsum[1] = __builtin_amdgcn_mfma_f32_16x16x32_bf16(p10, ones, lsum[1], 0, 0, 0);
    lsum[1] = __builtin_amdgcn_mfma_f32_16x16x32_bf16(p11, ones, lsum[1], 0, 0, 0);

    __syncthreads();   // drains prefetch (vmcnt0) + protects buffer reuse
  }

  // ---- normalize + store ----
#pragma unroll
  for (int sub = 0; sub < 2; ++sub)
#pragma unroll
    for (int r = 0; r < 4; ++r) {
      float rl = 1.0f / lsum[sub][r];
#pragma unroll
      for (int df = 0; df < 4; ++df) {
        float v = ctx[sub][df][r] * rl;
        O[(rowbase + q0 + sub * 16 + kg * 4 + r) * H_ + hcol + df * 16 + lr] = f2bf(v);
      }
    }
}

// ---------------- fused residual add + LayerNorm ----------------
template<int IN2_BF16, int WRITE_BF16>
__global__ __launch_bounds__(256) void add_ln(const float* __restrict__ X,
                                              const void* __restrict__ Y,
                                              const float* __restrict__ g,
                                              const float* __restrict__ beta,
                                              float* __restrict__ outF,
                                              unsigned short* __restrict__ outB) {
  const int row = blockIdx.x;
  const int tid = threadIdx.x;
  const int wave = tid >> 6, lane = tid & 63;
  __shared__ float red[8];

  float vals[4];
  float s = 0.0f, s2 = 0.0f;
#pragma unroll
  for (int i = 0; i < 4; ++i) {
    int c = i * 256 + tid;
    float v = X[(size_t)row * H_ + c];
    if (IN2_BF16) v += bf2f(reinterpret_cast<const unsigned short*>(Y)[(size_t)row * H_ + c]);
    else          v += reinterpret_cast<const float*>(Y)[(size_t)row * H_ + c];
    vals[i] = v;
    s += v;
    s2 += v * v;
  }
#pragma unroll
  for (int off = 32; off; off >>= 1) { s += __shfl_xor(s, off); s2 += __shfl_xor(s2, off); }
  if (lane == 0) { red[wave * 2] = s; red[wave * 2 + 1] = s2; }
  __syncthreads();
  s  = red[0] + red[2] + red[4] + red[6];
  s2 = red[1] + red[3] + red[5] + red[7];
  float mean = s * (1.0f / H_);
  float var  = s2 * (1.0f / H_) - mean * mean;
  float rstd = rsqrtf(var + 1e-5f);
#pragma unroll
  for (int i = 0; i < 4; ++i) {
    int c = i * 256 + tid;
    float v = (vals[i] - mean) * rstd * g[c] + beta[c];
    if (outF) outF[(size_t)row * H_ + c] = v;
    if (WRITE_BF16) outB[(size_t)row * H_ + c] = f2bf(v);
  }
}

// ---------------- orchestration ----------------
extern "C" void kernel_launch(void* const* d_in, const int* in_sizes, int n_in,
                              void* d_out, int out_size, void* d_ws, size_t ws_size,
                              hipStream_t stream) {
  const float* x  = (const float*)d_in[0];
  const float* Wq = (const float*)d_in[1];
  const float* bq = (const float*)d_in[2];
  const float* Wk = (const float*)d_in[3];
  const float* bk = (const float*)d_in[4];
  const float* Wv = (const float*)d_in[5];
  const float* bv = (const float*)d_in[6];
  const float* Wi = (const float*)d_in[7];
  const float* bi = (const float*)d_in[8];
  const float* Wo = (const float*)d_in[9];
  const float* bo = (const float*)d_in[10];
  const float* g1 = (const float*)d_in[11];
  const float* b1 = (const float*)d_in[12];
  const float* g2 = (const float*)d_in[13];
  const float* b2 = (const float*)d_in[14];

  unsigned char* ws = (unsigned char*)d_ws;
  size_t off = 0;
  auto alloc = [&](size_t bytes) { size_t o = off; off += (bytes + 255) & ~(size_t)255; return o; };

  unsigned short* xb  = (unsigned short*)(ws + alloc((size_t)M_ * H_ * 2));
  unsigned short* WqT = (unsigned short*)(ws + alloc((size_t)H_ * H_ * 2));
  unsigned short* WkT = (unsigned short*)(ws + alloc((size_t)H_ * H_ * 2));
  unsigned short* WvT = (unsigned short*)(ws + alloc((size_t)H_ * H_ * 2));
  unsigned short* WiT = (unsigned short*)(ws + alloc((size_t)H_ * FF_ * 2));
  unsigned short* WoT = (unsigned short*)(ws + alloc((size_t)FF_ * H_ * 2));
  unsigned short* qb  = (unsigned short*)(ws + alloc((size_t)M_ * H_ * 2));
  unsigned short* kb  = (unsigned short*)(ws + alloc((size_t)M_ * H_ * 2));
  unsigned short* vt  = (unsigned short*)(ws + alloc((size_t)M_ * H_ * 2));  // V^T [H][M]
  unsigned short* ao  = (unsigned short*)(ws + alloc((size_t)M_ * H_ * 2));
  float*          hf  = (float*)(ws + alloc((size_t)M_ * H_ * 4));
  unsigned short* hb  = (unsigned short*)(ws + alloc((size_t)M_ * H_ * 2));
  unsigned short* f1  = (unsigned short*)(ws + alloc((size_t)M_ * FF_ * 2));
  float*          f2  = (float*)(ws + alloc((size_t)M_ * H_ * 4));

  {
    int n4 = (int)((size_t)M_ * H_ / 4);
    cast_f32_bf16<<<(n4 + 255) / 256, 256, 0, stream>>>(x, xb, n4);
  }
  transpose_cast<<<dim3(H_ / 32, H_ / 32), 256, 0, stream>>>(Wq, WqT, H_, H_);
  transpose_cast<<<dim3(H_ / 32, H_ / 32), 256, 0, stream>>>(Wk, WkT, H_, H_);
  transpose_cast<<<dim3(H_ / 32, H_ / 32), 256, 0, stream>>>(Wv, WvT, H_, H_);
  transpose_cast<<<dim3(FF_ / 32, H_ / 32), 256, 0, stream>>>(Wi, WiT, H_, FF_);
  transpose_cast<<<dim3(H_ / 32, FF_ / 32), 256, 0, stream>>>(Wo, WoT, FF_, H_);

  const float QSCALE = 0.125f * 1.44269504088896340736f;  // fold /sqrt(64) and log2e into Q

  gemm_tn<0, 0, 0><<<dim3(M_ / 128, H_ / 128), 256, 0, stream>>>(xb, WqT, bq, qb, M_, H_, H_, QSCALE);
  gemm_tn<0, 0, 0><<<dim3(M_ / 128, H_ / 128), 256, 0, stream>>>(xb, WkT, bk, kb, M_, H_, H_, 1.0f);
  gemm_tn<0, 0, 1><<<dim3(H_ / 128, M_ / 128), 256, 0, stream>>>(WvT, xb, bv, vt, H_, M_, H_, 1.0f);

  attn_fwd<<<dim3(S_ / 128, B_ * NH_), 256, 0, stream>>>(qb, kb, vt, ao);

  add_ln<1, 1><<<M_, 256, 0, stream>>>(x, ao, g1, b1, hf, hb);

  gemm_tn<1, 0, 0><<<dim3(M_ / 128, FF_ / 128), 256, 0, stream>>>(hb, WiT, bi, f1, M_, FF_, H_, 1.0f);
  gemm_tn<0, 1, 0><<<dim3(M_ / 128, H_ / 128), 256, 0, stream>>>(f1, WoT, bo, f2, M_, H_, FF_, 1.0f);

  add_ln<0, 0><<<M_, 256, 0, stream>>>(hf, f2, g2, b2, (float*)d_out, nullptr);
}

// Round 4
// 502.453 us; speedup vs baseline: 2.5444x; 1.0968x over previous
//
#include <hip/hip_runtime.h>

// ---- problem constants ----
#define B_  4
#define S_  2048
#define H_  1024
#define NH_ 16
#define HD_ 64
#define FF_ 4096
#define M_  (B_*S_)   // 8192 rows

typedef __bf16 bf16x8 __attribute__((ext_vector_type(8)));
typedef float  f32x4  __attribute__((ext_vector_type(4)));
typedef unsigned short ushort8v __attribute__((ext_vector_type(8)));
typedef unsigned short ushort4v __attribute__((ext_vector_type(4)));

typedef __attribute__((address_space(1))) void GVOID;
typedef __attribute__((address_space(3))) void LVOID;

__device__ __forceinline__ void g2l16(const void* g, void* l) {
  __builtin_amdgcn_global_load_lds((GVOID*)g, (LVOID*)l, 16, 0, 0);
}

#if __has_builtin(__builtin_amdgcn_exp2f)
#define EXP2(x) __builtin_amdgcn_exp2f(x)
#else
#define EXP2(x) exp2f(x)
#endif

__device__ __forceinline__ unsigned short f2bf(float f) {
  unsigned int u = __float_as_uint(f);
  u += 0x7fffu + ((u >> 16) & 1u);
  return (unsigned short)(u >> 16);
}
__device__ __forceinline__ float bf2f(unsigned short h) {
  return __uint_as_float(((unsigned int)h) << 16);
}

// bijective XCD swizzle for grids with nwg % 8 == 0
__device__ __forceinline__ void xcd_swz(int& bx, int& by) {
  int gx = gridDim.x;
  int flat = by * gx + bx;
  int cpx = (gx * gridDim.y) >> 3;
  int swz = (flat & 7) * cpx + (flat >> 3);
  bx = swz % gx;
  by = swz / gx;
}

// ---------------- cast fp32 -> bf16 ----------------
__global__ __launch_bounds__(256) void cast_f32_bf16(const float* __restrict__ in,
                                                     unsigned short* __restrict__ out,
                                                     int n4) {
  int i = blockIdx.x * 256 + threadIdx.x;
  if (i >= n4) return;
  float4 v = reinterpret_cast<const float4*>(in)[i];
  ushort4v o;
  o[0] = f2bf(v.x); o[1] = f2bf(v.y); o[2] = f2bf(v.z); o[3] = f2bf(v.w);
  reinterpret_cast<ushort4v*>(out)[i] = o;
}

// ---------------- transpose + cast: W[R][C] f32 -> WT[C][R] bf16 ----------------
__global__ __launch_bounds__(256) void transpose_cast(const float* __restrict__ in,
                                                      unsigned short* __restrict__ out,
                                                      int R, int C) {
  __shared__ float t[32][33];
  const int bx = blockIdx.x * 32;
  const int by = blockIdx.y * 32;
  const int tx = threadIdx.x & 31, ty = threadIdx.x >> 5;
#pragma unroll
  for (int i = 0; i < 32; i += 8)
    t[ty + i][tx] = in[(size_t)(by + ty + i) * C + bx + tx];
  __syncthreads();
#pragma unroll
  for (int i = 0; i < 32; i += 8)
    out[(size_t)(bx + ty + i) * R + by + tx] = f2bf(t[tx][ty + i]);
}

// ---------------- TN GEMM: C[M,N] = act(A[M,K] @ Bt[N,K]^T + bias) * scale ------
// 2-phase double-buffered: stage(t+1) issued before compute(t), one barrier/iter.
template<int ACT, int OUT_F32, int BIAS_ROW>
__global__ __launch_bounds__(256) void gemm_tn(const unsigned short* __restrict__ A,
                                               const unsigned short* __restrict__ Bt,
                                               const float* __restrict__ bias,
                                               void* __restrict__ C,
                                               int M, int N, int K, float scale) {
  __shared__ unsigned short As[2][128 * 32];
  __shared__ unsigned short Bs[2][128 * 32];

  const int tid  = threadIdx.x;
  const int wave = tid >> 6;
  const int lane = tid & 63;
  const int kg   = lane >> 4;
  const int lr   = lane & 15;
  int bx = blockIdx.x, by = blockIdx.y;
  xcd_swz(bx, by);
  const int m0 = bx * 128;
  const int n0 = by * 128;
  const int wr = (wave >> 1) * 64;
  const int wc = (wave & 1) * 64;

  const int r0 = (wave * 2 + 0) * 16 + (lane >> 2);
  const int r1 = (wave * 2 + 1) * 16 + (lane >> 2);
  const int ke = ((lane & 3) * 8) ^ (((lane >> 3) & 3) << 3);
  const int swz = ((lr >> 1) & 3) << 3;

  const unsigned short* pA0 = &A [(size_t)(m0 + r0) * K + ke];
  const unsigned short* pA1 = &A [(size_t)(m0 + r1) * K + ke];
  const unsigned short* pB0 = &Bt[(size_t)(n0 + r0) * K + ke];
  const unsigned short* pB1 = &Bt[(size_t)(n0 + r1) * K + ke];

  auto stage = [&](int k0, int buf) {
    g2l16(pA0 + k0, &As[buf][(wave * 2 + 0) * 512]);
    g2l16(pA1 + k0, &As[buf][(wave * 2 + 1) * 512]);
    g2l16(pB0 + k0, &Bs[buf][(wave * 2 + 0) * 512]);
    g2l16(pB1 + k0, &Bs[buf][(wave * 2 + 1) * 512]);
  };

  f32x4 acc[4][4] = {};

  stage(0, 0);
  __syncthreads();

  const int nk = K >> 5;
  for (int t = 0; t < nk; ++t) {
    const int cur = t & 1;
    if (t + 1 < nk) stage((t + 1) << 5, cur ^ 1);

    bf16x8 af[4], bfr[4];
#pragma unroll
    for (int mi = 0; mi < 4; ++mi)
      af[mi] = *reinterpret_cast<const bf16x8*>(&As[cur][(wr + mi * 16 + lr) * 32 + ((kg * 8) ^ swz)]);
#pragma unroll
    for (int ni = 0; ni < 4; ++ni)
      bfr[ni] = *reinterpret_cast<const bf16x8*>(&Bs[cur][(wc + ni * 16 + lr) * 32 + ((kg * 8) ^ swz)]);
#pragma unroll
    for (int mi = 0; mi < 4; ++mi)
#pragma unroll
      for (int ni = 0; ni < 4; ++ni)
        acc[mi][ni] = __builtin_amdgcn_mfma_f32_16x16x32_bf16(af[mi], bfr[ni], acc[mi][ni], 0, 0, 0);

    __syncthreads();   // drains next-tile loads + protects cur for overwrite
  }

#pragma unroll
  for (int mi = 0; mi < 4; ++mi) {
#pragma unroll
    for (int ni = 0; ni < 4; ++ni) {
      int col = n0 + wc + ni * 16 + lr;
      float bc = (!BIAS_ROW && bias) ? bias[col] : 0.0f;
#pragma unroll
      for (int r = 0; r < 4; ++r) {
        int row = m0 + wr + mi * 16 + kg * 4 + r;
        float v = acc[mi][ni][r] + (BIAS_ROW ? bias[row] : bc);
        if (ACT == 1) v = 0.5f * v * (1.0f + erff(v * 0.70710678118f));
        v *= scale;
        if (OUT_F32) reinterpret_cast<float*>(C)[(size_t)row * N + col] = v;
        else reinterpret_cast<unsigned short*>(C)[(size_t)row * N + col] = f2bf(v);
      }
    }
  }
}

// ---------------- flash attention ----------------
// grid: (S/128, B*NH). 4 waves/block, each wave owns 32 q rows (2 subtiles of 16).
// Q pre-scaled by log2e/8 (exp2-domain). Double-buffered K/V; wave-shared max;
// row-sum via ones-MFMA; setprio around MFMA clusters.
__global__ __launch_bounds__(256) void attn_fwd(const unsigned short* __restrict__ Q,
                                                const unsigned short* __restrict__ Kb,
                                                const unsigned short* __restrict__ VT,
                                                unsigned short* __restrict__ O) {
  __shared__ unsigned short Ks[2][64 * 64];
  __shared__ unsigned short Vs[2][64 * 64];
  __shared__ __bf16 Ps[4][32 * 40];   // stride 40 elems

  const int tid  = threadIdx.x;
  const int wave = tid >> 6;
  const int lane = tid & 63;
  const int kg   = lane >> 4;
  const int lr   = lane & 15;
  int bx = blockIdx.x, by = blockIdx.y;
  xcd_swz(bx, by);
  const int b  = by >> 4;
  const int h  = by & 15;
  const size_t rowbase = (size_t)b * S_;
  const int hcol = h * 64;
  const int bcol0 = b * S_;
  const int q0 = bx * 128 + wave * 32;

  const int rT0 = (wave * 2 + 0) * 8 + (lane >> 3);
  const int rT1 = (wave * 2 + 1) * 8 + (lane >> 3);
  const int ce  = ((lane & 7) * 8) ^ (((lane >> 3) & 7) << 3);
  const int fswz = (lr & 7) << 3;

  bf16x8 qf[2][2];
#pragma unroll
  for (int sub = 0; sub < 2; ++sub)
#pragma unroll
    for (int d = 0; d < 2; ++d)
      qf[sub][d] = *reinterpret_cast<const bf16x8*>(
          &Q[(rowbase + q0 + sub * 16 + lr) * H_ + hcol + d * 32 + kg * 8]);

  bf16x8 ones;
#pragma unroll
  for (int i = 0; i < 8; ++i) ones[i] = (__bf16)1.0f;

  f32x4 ctx[2][4] = {};
  f32x4 lsum[2] = {};
  float m_w = -1e30f;

  auto stage = [&](int kt, int buf) {
    g2l16(&Kb[(rowbase + kt * 64 + rT0) * H_ + hcol + ce], &Ks[buf][(wave * 2 + 0) * 512]);
    g2l16(&Kb[(rowbase + kt * 64 + rT1) * H_ + hcol + ce], &Ks[buf][(wave * 2 + 1) * 512]);
    g2l16(&VT[(size_t)(hcol + rT0) * M_ + bcol0 + kt * 64 + ce], &Vs[buf][(wave * 2 + 0) * 512]);
    g2l16(&VT[(size_t)(hcol + rT1) * M_ + bcol0 + kt * 64 + ce], &Vs[buf][(wave * 2 + 1) * 512]);
  };

  stage(0, 0);
  __syncthreads();

  const int NT = S_ / 64;
  for (int kt = 0; kt < NT; ++kt) {
    const int cur = kt & 1;
    if (kt + 1 < NT) stage(kt + 1, cur ^ 1);

    // ---- QK^T ----
    f32x4 s0[4], s1[4];
    __builtin_amdgcn_s_setprio(1);
#pragma unroll
    for (int nf = 0; nf < 4; ++nf) {
      int row = nf * 16 + lr;
      bf16x8 kf0 = *reinterpret_cast<const bf16x8*>(&Ks[cur][row * 64 + ((kg * 8) ^ fswz)]);
      bf16x8 kf1 = *reinterpret_cast<const bf16x8*>(&Ks[cur][row * 64 + ((32 + kg * 8) ^ fswz)]);
      f32x4 z0 = {0.f, 0.f, 0.f, 0.f}, z1 = {0.f, 0.f, 0.f, 0.f};
      z0 = __builtin_amdgcn_mfma_f32_16x16x32_bf16(qf[0][0], kf0, z0, 0, 0, 0);
      z0 = __builtin_amdgcn_mfma_f32_16x16x32_bf16(qf[0][1], kf1, z0, 0, 0, 0);
      z1 = __builtin_amdgcn_mfma_f32_16x16x32_bf16(qf[1][0], kf0, z1, 0, 0, 0);
      z1 = __builtin_amdgcn_mfma_f32_16x16x32_bf16(qf[1][1], kf1, z1, 0, 0, 0);
      s0[nf] = z0;
      s1[nf] = z1;
    }
    __builtin_amdgcn_s_setprio(0);

    // ---- wave-shared max ----
    float mx = -1e30f;
#pragma unroll
    for (int nf = 0; nf < 4; ++nf)
#pragma unroll
      for (int r = 0; r < 4; ++r) {
        mx = fmaxf(mx, s0[nf][r]);
        mx = fmaxf(mx, s1[nf][r]);
      }
#pragma unroll
    for (int off = 1; off < 64; off <<= 1) mx = fmaxf(mx, __shfl_xor(mx, off));

    if (mx > m_w) {
      float sf = EXP2(m_w - mx);
      m_w = mx;
#pragma unroll
      for (int sub = 0; sub < 2; ++sub) {
#pragma unroll
        for (int df = 0; df < 4; ++df)
#pragma unroll
          for (int r = 0; r < 4; ++r) ctx[sub][df][r] *= sf;
#pragma unroll
        for (int r = 0; r < 4; ++r) lsum[sub][r] *= sf;
      }
    }

    // ---- P = exp2(s - m) -> wave-private LDS ----
#pragma unroll
    for (int nf = 0; nf < 4; ++nf)
#pragma unroll
      for (int r = 0; r < 4; ++r) {
        Ps[wave][(0 * 16 + kg * 4 + r) * 40 + nf * 16 + lr] = (__bf16)EXP2(s0[nf][r] - m_w);
        Ps[wave][(1 * 16 + kg * 4 + r) * 40 + nf * 16 + lr] = (__bf16)EXP2(s1[nf][r] - m_w);
      }

    // ---- PV + row-sum via ones-MFMA ----
    bf16x8 p00 = *reinterpret_cast<const bf16x8*>(&Ps[wave][(0 * 16 + lr) * 40 + kg * 8]);
    bf16x8 p01 = *reinterpret_cast<const bf16x8*>(&Ps[wave][(0 * 16 + lr) * 40 + 32 + kg * 8]);
    bf16x8 p10 = *reinterpret_cast<const bf16x8*>(&Ps[wave][(1 * 16 + lr) * 40 + kg * 8]);
    bf16x8 p11 = *reinterpret_cast<const bf16x8*>(&Ps[wave][(1 * 16 + lr) * 40 + 32 + kg * 8]);
    __builtin_amdgcn_s_setprio(1);
#pragma unroll
    for (int df = 0; df < 4; ++df) {
      int row = df * 16 + lr;
      bf16x8 vf0 = *reinterpret_cast<const bf16x8*>(&Vs[cur][row * 64 + ((kg * 8) ^ fswz)]);
      bf16x8 vf1 = *reinterpret_cast<const bf16x8*>(&Vs[cur][row * 64 + ((32 + kg * 8) ^ fswz)]);
      ctx[0][df] = __builtin_amdgcn_mfma_f32_16x16x32_bf16(p00, vf0, ctx[0][df], 0, 0, 0);
      ctx[0][df] = __builtin_amdgcn_mfma_f32_16x16x32_bf16(p01, vf1, ctx[0][df], 0, 0, 0);
      ctx[1][df] = __builtin_amdgcn_mfma_f32_16x16x32_bf16(p10, vf0, ctx[1][df], 0, 0, 0);
      ctx[1][df] = __builtin_amdgcn_mfma_f32_16x16x32_bf16(p11, vf1, ctx[1][df], 0, 0, 0);
    }
    lsum[0] = __builtin_amdgcn_mfma_f32_16x16x32_bf16(p00, ones, lsum[0], 0, 0, 0);
    lsum[0] = __builtin_amdgcn_mfma_f32_16x16x32_bf16(p01, ones, lsum[0], 0, 0, 0);
    lsum[1] = __builtin_amdgcn_mfma_f32_16x16x32_bf16(p10, ones, lsum[1], 0, 0, 0);
    lsum[1] = __builtin_amdgcn_mfma_f32_16x16x32_bf16(p11, ones, lsum[1], 0, 0, 0);
    __builtin_amdgcn_s_setprio(0);

    __syncthreads();
  }

  // ---- normalize + store ----
#pragma unroll
  for (int sub = 0; sub < 2; ++sub)
#pragma unroll
    for (int r = 0; r < 4; ++r) {
      float rl = 1.0f / lsum[sub][r];
#pragma unroll
      for (int df = 0; df < 4; ++df) {
        float v = ctx[sub][df][r] * rl;
        O[(rowbase + q0 + sub * 16 + kg * 4 + r) * H_ + hcol + df * 16 + lr] = f2bf(v);
      }
    }
}

// ---------------- fused residual add + LayerNorm ----------------
template<int IN2_BF16, int WRITE_BF16>
__global__ __launch_bounds__(256) void add_ln(const float* __restrict__ X,
                                              const void* __restrict__ Y,
                                              const float* __restrict__ g,
                                              const float* __restrict__ beta,
                                              float* __restrict__ outF,
                                              unsigned short* __restrict__ outB) {
  const int row = blockIdx.x;
  const int tid = threadIdx.x;
  const int wave = tid >> 6, lane = tid & 63;
  __shared__ float red[8];

  float vals[4];
  float s = 0.0f, s2 = 0.0f;
#pragma unroll
  for (int i = 0; i < 4; ++i) {
    int c = i * 256 + tid;
    float v = X[(size_t)row * H_ + c];
    if (IN2_BF16) v += bf2f(reinterpret_cast<const unsigned short*>(Y)[(size_t)row * H_ + c]);
    else          v += reinterpret_cast<const float*>(Y)[(size_t)row * H_ + c];
    vals[i] = v;
    s += v;
    s2 += v * v;
  }
#pragma unroll
  for (int off = 32; off; off >>= 1) { s += __shfl_xor(s, off); s2 += __shfl_xor(s2, off); }
  if (lane == 0) { red[wave * 2] = s; red[wave * 2 + 1] = s2; }
  __syncthreads();
  s  = red[0] + red[2] + red[4] + red[6];
  s2 = red[1] + red[3] + red[5] + red[7];
  float mean = s * (1.0f / H_);
  float var  = s2 * (1.0f / H_) - mean * mean;
  float rstd = rsqrtf(var + 1e-5f);
#pragma unroll
  for (int i = 0; i < 4; ++i) {
    int c = i * 256 + tid;
    float v = (vals[i] - mean) * rstd * g[c] + beta[c];
    if (outF) outF[(size_t)row * H_ + c] = v;
    if (WRITE_BF16) outB[(size_t)row * H_ + c] = f2bf(v);
  }
}

// ---------------- orchestration ----------------
extern "C" void kernel_launch(void* const* d_in, const int* in_sizes, int n_in,
                              void* d_out, int out_size, void* d_ws, size_t ws_size,
                              hipStream_t stream) {
  const float* x  = (const float*)d_in[0];
  const float* Wq = (const float*)d_in[1];
  const float* bq = (const float*)d_in[2];
  const float* Wk = (const float*)d_in[3];
  const float* bk = (const float*)d_in[4];
  const float* Wv = (const float*)d_in[5];
  const float* bv = (const float*)d_in[6];
  const float* Wi = (const float*)d_in[7];
  const float* bi = (const float*)d_in[8];
  const float* Wo = (const float*)d_in[9];
  const float* bo = (const float*)d_in[10];
  const float* g1 = (const float*)d_in[11];
  const float* b1 = (const float*)d_in[12];
  const float* g2 = (const float*)d_in[13];
  const float* b2 = (const float*)d_in[14];

  unsigned char* ws = (unsigned char*)d_ws;
  size_t off = 0;
  auto alloc = [&](size_t bytes) { size_t o = off; off += (bytes + 255) & ~(size_t)255; return o; };

  unsigned short* xb  = (unsigned short*)(ws + alloc((size_t)M_ * H_ * 2));
  unsigned short* WqT = (unsigned short*)(ws + alloc((size_t)H_ * H_ * 2));
  unsigned short* WkT = (unsigned short*)(ws + alloc((size_t)H_ * H_ * 2));
  unsigned short* WvT = (unsigned short*)(ws + alloc((size_t)H_ * H_ * 2));
  unsigned short* WiT = (unsigned short*)(ws + alloc((size_t)H_ * FF_ * 2));
  unsigned short* WoT = (unsigned short*)(ws + alloc((size_t)FF_ * H_ * 2));
  unsigned short* qb  = (unsigned short*)(ws + alloc((size_t)M_ * H_ * 2));
  unsigned short* kb  = (unsigned short*)(ws + alloc((size_t)M_ * H_ * 2));
  unsigned short* vt  = (unsigned short*)(ws + alloc((size_t)M_ * H_ * 2));  // V^T [H][M]
  unsigned short* ao  = (unsigned short*)(ws + alloc((size_t)M_ * H_ * 2));
  float*          hf  = (float*)(ws + alloc((size_t)M_ * H_ * 4));
  unsigned short* hb  = (unsigned short*)(ws + alloc((size_t)M_ * H_ * 2));
  unsigned short* f1  = (unsigned short*)(ws + alloc((size_t)M_ * FF_ * 2));
  float*          f2  = (float*)(ws + alloc((size_t)M_ * H_ * 4));

  {
    int n4 = (int)((size_t)M_ * H_ / 4);
    cast_f32_bf16<<<(n4 + 255) / 256, 256, 0, stream>>>(x, xb, n4);
  }
  transpose_cast<<<dim3(H_ / 32, H_ / 32), 256, 0, stream>>>(Wq, WqT, H_, H_);
  transpose_cast<<<dim3(H_ / 32, H_ / 32), 256, 0, stream>>>(Wk, WkT, H_, H_);
  transpose_cast<<<dim3(H_ / 32, H_ / 32), 256, 0, stream>>>(Wv, WvT, H_, H_);
  transpose_cast<<<dim3(FF_ / 32, H_ / 32), 256, 0, stream>>>(Wi, WiT, H_, FF_);
  transpose_cast<<<dim3(H_ / 32, FF_ / 32), 256, 0, stream>>>(Wo, WoT, FF_, H_);

  const float QSCALE = 0.125f * 1.44269504088896340736f;

  gemm_tn<0, 0, 0><<<dim3(M_ / 128, H_ / 128), 256, 0, stream>>>(xb, WqT, bq, qb, M_, H_, H_, QSCALE);
  gemm_tn<0, 0, 0><<<dim3(M_ / 128, H_ / 128), 256, 0, stream>>>(xb, WkT, bk, kb, M_, H_, H_, 1.0f);
  gemm_tn<0, 0, 1><<<dim3(H_ / 128, M_ / 128), 256, 0, stream>>>(WvT, xb, bv, vt, H_, M_, H_, 1.0f);

  attn_fwd<<<dim3(S_ / 128, B_ * NH_), 256, 0, stream>>>(qb, kb, vt, ao);

  add_ln<1, 1><<<M_, 256, 0, stream>>>(x, ao, g1, b1, hf, hb);

  gemm_tn<1, 0, 0><<<dim3(M_ / 128, FF_ / 128), 256, 0, stream>>>(hb, WiT, bi, f1, M_, FF_, H_, 1.0f);
  gemm_tn<0, 1, 0><<<dim3(M_ / 128, H_ / 128), 256, 0, stream>>>(f1, WoT, bo, f2, M_, H_, FF_, 1.0f);

  add_ln<0, 0><<<M_, 256, 0, stream>>>(hf, f2, g2, b2, (float*)d_out, nullptr);
}